// Round 8
// baseline (134.012 us; speedup 1.0000x reference)
//
#include <hip/hip_runtime.h>

// ---------------------------------------------------------------------------
// VisionEncoder (PASSING since R12, absmax 1.95e-3): project -> SAT -> fused
// pool/LN/GEMM2. V4 coordinate semantics (XLA reciprocal-multiply) verified.
//
// R22: gemm_u occupancy push, continuing R14's proven direction (344->688
//   blocks was that session's win; VALUBusy was still only ~23% at 688
//   blocks = 2.7/CU). Tile 64x128 -> 32x128 rows => grid 172x8 = 1376
//   blocks (5.4/CU). Per-output kk order unchanged, split-K unchanged ->
//   bit-identical output. LDS 24->20KB, acc 32->16 VGPR. A-staging becomes
//   exactly 1 DMA call/thread (dest byte = t*16). All other kernels
//   byte-identical to R21 (passing, DMA-staged).
//   K1 gemm_u  : 32x128 tile, 4x4 micro, split-K=8 -> 1376 blocks
//   K2 prefix_x: grid (nph,2), 64 ch/block, sums 8 partials, x-scan -> SAT
//   K3 prefix_y: grid (npw+1,2), 64 ch/block, y-scan in LDS (DMA staged)
//   K4 pool_proj: parallel LN stats; W2 staged via DMA
// ---------------------------------------------------------------------------

#define HD 128
#define SPLITK 8

#define GLOBAL_AS __attribute__((address_space(1)))
#define LDS_AS    __attribute__((address_space(3)))

__device__ __forceinline__ int decode_dim(const int* p, int fallback) {
    if (p == nullptr) return fallback;
    int vi = *p;
    if (vi >= 1 && vi <= 1000000) return vi;
    float vf = __int_as_float(vi);
    if (vf >= 1.0f && vf <= 1000000.0f) return (int)vf;
    return fallback;
}

// V4 (verified R12): trunc( fl32( fl32(x * fl32(1/W)) * n ) ), bit-exact via
// f64; optnone so no fast-math rewrite can touch it.
__attribute__((noinline, optnone))
__device__ int coord_map(int x, int W, int n) {
    double rd = 1.0 / (double)W;
    float r = (float)rd;
    double qd = (double)x * (double)r;
    float q = (float)qd;
    double pd = (double)q * (double)n;
    float p = (float)pd;
    return (int)p;
}

// ---------------------------------------------------------------------------
// K1: partial GEMM, tile 32 rows x 128 cols, K-chunk = E/8.
// Both tiles staged via global_load_lds width=16.
//   As[32][32] row-major unpadded: thread t covers byte t*16
//     == As[t>>3][(t&7)*4]  (wave-uniform base + lane*16: legal).
//   Bs[32][128]: 4 DMA calls/wave (verified R20).
// Inner loop: kk in quads, per-acc adds kk-ascending (bit-identical to the
// original per-kk loop). 2 distinct tr per wave -> As reads 2-way (free).
// ---------------------------------------------------------------------------
__global__ __launch_bounds__(256) void gemm_u_kernel(
    const float* __restrict__ T, const float* __restrict__ W1,
    float* __restrict__ U, int P, int E)
{
    __shared__ float As[32][32];    // [row][kk] row-major, UNPADDED (DMA dest)
    __shared__ float Bs[32][HD];    // [kk][col]

    int t  = threadIdx.x;
    int tc = t & 31;                // cols tc*4 .. tc*4+3
    int tr = t >> 5;                // rows tr*4 .. tr*4+3
    int row0 = blockIdx.x * 32;
    int ks   = blockIdx.y;
    int kchunk = E >> 3;            // 128
    int kbase  = ks * kchunk;
    float* Uo = U + (size_t)ks * (size_t)P * HD;

    float acc[4][4];
#pragma unroll
    for (int r = 0; r < 4; ++r)
#pragma unroll
        for (int j = 0; j < 4; ++j) acc[r][j] = 0.f;

    int a_row = t >> 3;             // 0..31
    int a_col = (t & 7) * 4;        // k offset
    int brow = t >> 5;              // 0..7
    int bc   = (t & 31) * 4;

    for (int kt = 0; kt < kchunk; kt += 32) {
        int k0 = kbase + kt;
        {   // stage A: 1 DMA call per thread (dest byte = t*16)
            int rg = row0 + a_row; if (rg >= P) rg = P - 1;
            __builtin_amdgcn_global_load_lds(
                (const GLOBAL_AS unsigned int*)&T[(size_t)rg * E + k0 + a_col],
                (LDS_AS unsigned int*)&As[a_row][a_col], 16, 0, 0);
        }
        {   // stage B: 4 DMA calls per wave (verified R20)
#pragma unroll
            for (int i = 0; i < 4; ++i) {
                int kk = brow + i * 8;
                __builtin_amdgcn_global_load_lds(
                    (const GLOBAL_AS unsigned int*)&W1[(size_t)(k0 + kk) * HD + bc],
                    (LDS_AS unsigned int*)&Bs[kk][bc], 16, 0, 0);
            }
        }
        __syncthreads();

#pragma unroll
        for (int q = 0; q < 8; ++q) {
            float4 b0 = *(const float4*)&Bs[q * 4 + 0][tc * 4];
            float4 b1 = *(const float4*)&Bs[q * 4 + 1][tc * 4];
            float4 b2 = *(const float4*)&Bs[q * 4 + 2][tc * 4];
            float4 b3 = *(const float4*)&Bs[q * 4 + 3][tc * 4];
#pragma unroll
            for (int r = 0; r < 4; ++r) {
                float4 a = *(const float4*)&As[tr * 4 + r][q * 4];
                acc[r][0] += a.x * b0.x; acc[r][1] += a.x * b0.y;
                acc[r][2] += a.x * b0.z; acc[r][3] += a.x * b0.w;
                acc[r][0] += a.y * b1.x; acc[r][1] += a.y * b1.y;
                acc[r][2] += a.y * b1.z; acc[r][3] += a.y * b1.w;
                acc[r][0] += a.z * b2.x; acc[r][1] += a.z * b2.y;
                acc[r][2] += a.z * b2.z; acc[r][3] += a.z * b2.w;
                acc[r][0] += a.w * b3.x; acc[r][1] += a.w * b3.y;
                acc[r][2] += a.w * b3.z; acc[r][3] += a.w * b3.w;
            }
        }
        __syncthreads();
    }

#pragma unroll
    for (int r = 0; r < 4; ++r) {
        int p = row0 + tr * 4 + r;
        if (p < P) {
            float4 v = make_float4(acc[r][0], acc[r][1], acc[r][2], acc[r][3]);
            *(float4*)&Uo[(size_t)p * HD + tc * 4] = v;
        }
    }
}

// ---------------------------------------------------------------------------
// K2: block (y, chalf): sum SPLITK partials of row y (74 x 64ch), x-scan,
// write SAT row y+1 (+ col-0 border). (staging sums partials -> no DMA)
// ---------------------------------------------------------------------------
__global__ __launch_bounds__(256) void prefix_x_kernel(
    const float* __restrict__ U, float* __restrict__ S,
    int P, int npw, int nph)
{
    extern __shared__ float tile[];            // npw*64 floats
    int t = threadIdx.x;
    int y = blockIdx.x;
    int ch0 = blockIdx.y * 64;
    size_t ustride = (size_t)P * HD;
    size_t ubase = (size_t)y * npw * HD + ch0;

    int nj = npw * 16;                         // float4 groups
    for (int j = t; j < nj; j += 256) {
        int x = j >> 4, cq = (j & 15) * 4;
        size_t off = ubase + (size_t)x * HD + cq;
        float4 s = *(const float4*)(U + off);
#pragma unroll
        for (int p = 1; p < SPLITK; ++p) {
            float4 v = *(const float4*)(U + (size_t)p * ustride + off);
            s.x += v.x; s.y += v.y; s.z += v.z; s.w += v.w;
        }
        *(float4*)&tile[x * 64 + cq] = s;
    }
    __syncthreads();

    if (t < 64) {
        int c = t;
        size_t srow = (size_t)(y + 1) * (npw + 1) * HD + ch0;
        S[srow + c] = 0.f;                     // col-0 border
        float acc = 0.f;
        for (int x = 0; x < npw; ++x) {
            acc += tile[x * 64 + c];
            S[srow + (size_t)(x + 1) * HD + c] = acc;
        }
    }
}

// ---------------------------------------------------------------------------
// K3: block (x, chalf): stage column x (y=1..nph) through LDS via DMA
// (dest = round*4096 + t*16, wave-uniform + lane*16), y-scan, write back.
// ---------------------------------------------------------------------------
__global__ __launch_bounds__(256) void prefix_y_kernel(
    float* __restrict__ S, int npw, int nph)
{
    extern __shared__ float tile[];            // nph*64 floats
    int t = threadIdx.x;
    int x = blockIdx.x;
    int ch0 = blockIdx.y * 64;
    size_t stride = (size_t)(npw + 1) * HD;
    size_t base = (size_t)x * HD + ch0;

    int nj = nph * 16;
    for (int j = t; j < nj; j += 256) {
        int y = j >> 4, cq = (j & 15) * 4;
        __builtin_amdgcn_global_load_lds(
            (const GLOBAL_AS unsigned int*)(S + base + (size_t)(y + 1) * stride + cq),
            (LDS_AS unsigned int*)&tile[y * 64 + cq], 16, 0, 0);
    }
    __syncthreads();

    if (t < 64) {
        int c = t;
        S[base + c] = 0.f;                     // row-0 border
        float acc = 0.f;
        for (int y = 0; y < nph; ++y) {
            acc += tile[y * 64 + c];
            S[base + (size_t)(y + 1) * stride + c] = acc;
        }
    }
}

// ---------------------------------------------------------------------------
// K4: 16 boxes x 128 cols; parallel LN stats; fp32 out. W2 staged via DMA
// (call i: dest byte = i*4096 + t*16 == Bs[i*8 + t>>5][(t&31)*4]).
// ---------------------------------------------------------------------------
__global__ __launch_bounds__(256) void pool_proj_kernel(
    const float* __restrict__ S, const int* __restrict__ bboxes,
    const int* __restrict__ pH, const int* __restrict__ pW,
    const float* __restrict__ b1, const float* __restrict__ gamma,
    const float* __restrict__ beta, const float* __restrict__ W2,
    const float* __restrict__ b2, float* __restrict__ out,
    int Nb, int npw, int nph, int fbW, int fbH)
{
    __shared__ float hs[16][HD + 1];
    __shared__ float Bs[32][HD];
    __shared__ float red_s[16][17], red_q[16][17];
    __shared__ int   cI11[16], cI12[16], cI21[16], cI22[16];
    __shared__ float cCnt[16];
    __shared__ float mu_s[16], rs_s[16];

    int t = threadIdx.x;
    int c = t & 127;
    int rh = t >> 7;
    int row0 = blockIdx.x * 16;

    if (t < 16) {
        int b = row0 + t; if (b >= Nb) b = Nb - 1;
        int x1 = bboxes[b * 4 + 0];
        int y1 = bboxes[b * 4 + 1];
        int x2 = bboxes[b * 4 + 2];
        int y2 = bboxes[b * 4 + 3];
        int Wi = decode_dim(pW, fbW);
        int Hi = decode_dim(pH, fbH);
        int px1 = coord_map(x1, Wi, npw);
        int px2 = coord_map(x2, Wi, npw);
        int py1 = coord_map(y1, Hi, nph);
        int py2 = coord_map(y2, Hi, nph);
        px1 = min(max(px1, 0), npw - 1);
        px2 = max(px1 + 1, min(px2, npw));
        py1 = min(max(py1, 0), nph - 1);
        py2 = max(py1 + 1, min(py2, nph));
        int st = npw + 1;
        cI11[t] = (py1 * st + px1) * HD;
        cI12[t] = (py1 * st + px2) * HD;
        cI21[t] = (py2 * st + px1) * HD;
        cI22[t] = (py2 * st + px2) * HD;
        cCnt[t] = (float)((py2 - py1) * (px2 - px1));
    }
    __syncthreads();

    float bias1 = b1[c];
    float hv[8];
#pragma unroll
    for (int r = 0; r < 8; ++r) {
        int row = rh * 8 + r;
        float s = S[cI22[row] + c] - S[cI12[row] + c]
                - S[cI21[row] + c] + S[cI11[row] + c];
        hv[r] = s / cCnt[row] + bias1;
        hs[row][c] = hv[r];
    }
    __syncthreads();

    // parallel LN stats: 16 threads per row, 8 elements each
    {
        int sr = t & 15;           // row
        int sg = t >> 4;           // group 0..15
        float ps = 0.f, pq = 0.f;
#pragma unroll
        for (int i = 0; i < 8; ++i) {
            float v = hs[sr][sg * 8 + i];
            ps += v; pq += v * v;
        }
        red_s[sr][sg] = ps; red_q[sr][sg] = pq;
    }
    __syncthreads();
    if (t < 16) {
        float s = 0.f, q = 0.f;
#pragma unroll
        for (int i = 0; i < 16; ++i) { s += red_s[t][i]; q += red_q[t][i]; }
        float m = s * (1.0f / HD);
        float v = q * (1.0f / HD) - m * m;
        mu_s[t] = m;
        rs_s[t] = rsqrtf(v + 1e-5f);
    }
    __syncthreads();

    float g = gamma[c], be = beta[c];
#pragma unroll
    for (int r = 0; r < 8; ++r) {
        int row = rh * 8 + r;
        float x = (hv[r] - mu_s[row]) * rs_s[row] * g + be;
        hs[row][c] = fmaxf(x, 0.f);
    }
    __syncthreads();

    float bias2 = b2[c];
    float acc2[8];
#pragma unroll
    for (int r = 0; r < 8; ++r) acc2[r] = bias2;
    for (int k0 = 0; k0 < HD; k0 += 32) {
#pragma unroll
        for (int i = 0; i < 4; ++i) {
            int kk = i * 8 + (t >> 5);
            int cc = (t & 31) * 4;
            __builtin_amdgcn_global_load_lds(
                (const GLOBAL_AS unsigned int*)&W2[(size_t)(k0 + kk) * HD + cc],
                (LDS_AS unsigned int*)&Bs[kk][cc], 16, 0, 0);
        }
        __syncthreads();
#pragma unroll
        for (int kk = 0; kk < 32; ++kk) {
            float bv = Bs[kk][c];
#pragma unroll
            for (int r = 0; r < 8; ++r)
                acc2[r] += hs[rh * 8 + r][k0 + kk] * bv;
        }
        __syncthreads();
    }

#pragma unroll
    for (int r = 0; r < 8; ++r) {
        int rg = row0 + rh * 8 + r;
        if (rg < Nb) out[(size_t)rg * HD + c] = acc2[r];
    }
}

extern "C" void kernel_launch(void* const* d_in, const int* in_sizes, int n_in,
                              void* d_out, int out_size, void* d_ws, size_t ws_size,
                              hipStream_t stream) {
    int iT = 0, iB = 1, iH = 2, iW = 3, iW1 = 4, ib1 = 5, ig = 6, ibe = 7,
        iW2 = 8, ib2 = 9;
    bool has_scalars = (n_in >= 10 && in_sizes[2] == 1 && in_sizes[3] == 1);
    if (!has_scalars) { iW1 = 2; ib1 = 3; ig = 4; ibe = 5; iW2 = 6; ib2 = 7; }

    const float* tokens = (const float*)d_in[iT];
    const int*   bboxes = (const int*)d_in[iB];
    const int*   pH     = has_scalars ? (const int*)d_in[iH] : nullptr;
    const int*   pW     = has_scalars ? (const int*)d_in[iW] : nullptr;
    const float* W1     = (const float*)d_in[iW1];
    const float* b1     = (const float*)d_in[ib1];
    const float* gamma  = (const float*)d_in[ig];
    const float* beta   = (const float*)d_in[ibe];
    const float* W2     = (const float*)d_in[iW2];
    const float* b2     = (const float*)d_in[ib2];
    float* out = (float*)d_out;

    int Hd = in_sizes[ib1];               // 128
    int E  = in_sizes[iW1] / Hd;          // 1024
    int Nb = in_sizes[iB] / 4;            // 4096
    int P  = in_sizes[iT] / E;            // 5476
    int npw = 1;
    while ((npw + 1) * (npw + 1) <= P) ++npw;  // 74
    int nph = P / npw;
    (void)out_size; (void)ws_size;

    // Workspace: S (2.88 MB) + 8 partial U buffers (22.4 MB) = 25.3 MB
    float* S = (float*)d_ws;
    size_t s_elems = ((size_t)(nph + 1) * (npw + 1) * HD + 255) & ~(size_t)255;
    float* U = S + s_elems;

    int mtiles = (P + 31) / 32;
    gemm_u_kernel<<<dim3(mtiles, SPLITK), dim3(256), 0, stream>>>(
        tokens, W1, U, P, E);
    prefix_x_kernel<<<dim3(nph, 2), dim3(256), (size_t)npw * 64 * 4, stream>>>(
        U, S, P, npw, nph);
    prefix_y_kernel<<<dim3(npw + 1, 2), dim3(256), (size_t)nph * 64 * 4, stream>>>(
        S, npw, nph);
    pool_proj_kernel<<<dim3((Nb + 15) / 16), dim3(256), 0, stream>>>(
        S, bboxes, pH, pW, b1, gamma, beta, W2, b2, out, Nb, npw, nph,
        14 * npw, 14 * nph);
}

// Round 9
// 133.347 us; speedup vs baseline: 1.0050x; 1.0050x over previous
//
#include <hip/hip_runtime.h>

// ---------------------------------------------------------------------------
// VisionEncoder (PASSING since R12): project -> SAT -> fused pool/LN/GEMM2.
// V4 coordinate semantics (XLA reciprocal-multiply) verified.
//
// R23: split-K traffic cut. R8 proved gemm block count is irrelevant
//   (688 vs 1376 identical) -> SPLITK 8->4 acts purely through its traffic
//   mechanism: U round-trip 44.8 -> 22.4 MB (saves ~3.5us HBM time).
//   Everything else byte-identical to R22 (passing). Numerics: summation
//   regrouping only (256-k in-order chains, 4 partials summed ascending);
//   tolerance proven >= 3.9e-3 by R1's pass.
//   K1 gemm_u  : 32x128 tile, 4x4 micro, split-K=4 -> 688 blocks, DMA staged
//   K2 prefix_x: grid (nph,2), 64 ch/block, sums 4 partials, x-scan -> SAT
//   K3 prefix_y: grid (npw+1,2), 64 ch/block, y-scan in LDS (DMA staged)
//   K4 pool_proj: parallel LN stats; W2 staged via DMA
// ---------------------------------------------------------------------------

#define HD 128
#define SPLITK 4

#define GLOBAL_AS __attribute__((address_space(1)))
#define LDS_AS    __attribute__((address_space(3)))

__device__ __forceinline__ int decode_dim(const int* p, int fallback) {
    if (p == nullptr) return fallback;
    int vi = *p;
    if (vi >= 1 && vi <= 1000000) return vi;
    float vf = __int_as_float(vi);
    if (vf >= 1.0f && vf <= 1000000.0f) return (int)vf;
    return fallback;
}

// V4 (verified R12): trunc( fl32( fl32(x * fl32(1/W)) * n ) ), bit-exact via
// f64; optnone so no fast-math rewrite can touch it.
__attribute__((noinline, optnone))
__device__ int coord_map(int x, int W, int n) {
    double rd = 1.0 / (double)W;
    float r = (float)rd;
    double qd = (double)x * (double)r;
    float q = (float)qd;
    double pd = (double)q * (double)n;
    float p = (float)pd;
    return (int)p;
}

// ---------------------------------------------------------------------------
// K1: partial GEMM, tile 32 rows x 128 cols, K-chunk = E/4 = 256.
// Both tiles staged via global_load_lds width=16.
//   As[32][32] row-major unpadded: thread t covers byte t*16
//     == As[t>>3][(t&7)*4]  (wave-uniform base + lane*16: legal).
//   Bs[32][128]: 4 DMA calls/wave (verified R20).
// Inner loop: kk in quads, per-acc adds kk-ascending. 2 distinct tr per
// wave -> As reads 2-way (free).
// ---------------------------------------------------------------------------
__global__ __launch_bounds__(256) void gemm_u_kernel(
    const float* __restrict__ T, const float* __restrict__ W1,
    float* __restrict__ U, int P, int E)
{
    __shared__ float As[32][32];    // [row][kk] row-major, UNPADDED (DMA dest)
    __shared__ float Bs[32][HD];    // [kk][col]

    int t  = threadIdx.x;
    int tc = t & 31;                // cols tc*4 .. tc*4+3
    int tr = t >> 5;                // rows tr*4 .. tr*4+3
    int row0 = blockIdx.x * 32;
    int ks   = blockIdx.y;
    int kchunk = E / SPLITK;        // 256
    int kbase  = ks * kchunk;
    float* Uo = U + (size_t)ks * (size_t)P * HD;

    float acc[4][4];
#pragma unroll
    for (int r = 0; r < 4; ++r)
#pragma unroll
        for (int j = 0; j < 4; ++j) acc[r][j] = 0.f;

    int a_row = t >> 3;             // 0..31
    int a_col = (t & 7) * 4;        // k offset
    int brow = t >> 5;              // 0..7
    int bc   = (t & 31) * 4;

    for (int kt = 0; kt < kchunk; kt += 32) {
        int k0 = kbase + kt;
        {   // stage A: 1 DMA call per thread (dest byte = t*16)
            int rg = row0 + a_row; if (rg >= P) rg = P - 1;
            __builtin_amdgcn_global_load_lds(
                (const GLOBAL_AS unsigned int*)&T[(size_t)rg * E + k0 + a_col],
                (LDS_AS unsigned int*)&As[a_row][a_col], 16, 0, 0);
        }
        {   // stage B: 4 DMA calls per wave (verified R20)
#pragma unroll
            for (int i = 0; i < 4; ++i) {
                int kk = brow + i * 8;
                __builtin_amdgcn_global_load_lds(
                    (const GLOBAL_AS unsigned int*)&W1[(size_t)(k0 + kk) * HD + bc],
                    (LDS_AS unsigned int*)&Bs[kk][bc], 16, 0, 0);
            }
        }
        __syncthreads();

#pragma unroll
        for (int q = 0; q < 8; ++q) {
            float4 b0 = *(const float4*)&Bs[q * 4 + 0][tc * 4];
            float4 b1 = *(const float4*)&Bs[q * 4 + 1][tc * 4];
            float4 b2 = *(const float4*)&Bs[q * 4 + 2][tc * 4];
            float4 b3 = *(const float4*)&Bs[q * 4 + 3][tc * 4];
#pragma unroll
            for (int r = 0; r < 4; ++r) {
                float4 a = *(const float4*)&As[tr * 4 + r][q * 4];
                acc[r][0] += a.x * b0.x; acc[r][1] += a.x * b0.y;
                acc[r][2] += a.x * b0.z; acc[r][3] += a.x * b0.w;
                acc[r][0] += a.y * b1.x; acc[r][1] += a.y * b1.y;
                acc[r][2] += a.y * b1.z; acc[r][3] += a.y * b1.w;
                acc[r][0] += a.z * b2.x; acc[r][1] += a.z * b2.y;
                acc[r][2] += a.z * b2.z; acc[r][3] += a.z * b2.w;
                acc[r][0] += a.w * b3.x; acc[r][1] += a.w * b3.y;
                acc[r][2] += a.w * b3.z; acc[r][3] += a.w * b3.w;
            }
        }
        __syncthreads();
    }

#pragma unroll
    for (int r = 0; r < 4; ++r) {
        int p = row0 + tr * 4 + r;
        if (p < P) {
            float4 v = make_float4(acc[r][0], acc[r][1], acc[r][2], acc[r][3]);
            *(float4*)&Uo[(size_t)p * HD + tc * 4] = v;
        }
    }
}

// ---------------------------------------------------------------------------
// K2: block (y, chalf): sum SPLITK partials of row y (74 x 64ch), x-scan,
// write SAT row y+1 (+ col-0 border). (staging sums partials -> no DMA)
// ---------------------------------------------------------------------------
__global__ __launch_bounds__(256) void prefix_x_kernel(
    const float* __restrict__ U, float* __restrict__ S,
    int P, int npw, int nph)
{
    extern __shared__ float tile[];            // npw*64 floats
    int t = threadIdx.x;
    int y = blockIdx.x;
    int ch0 = blockIdx.y * 64;
    size_t ustride = (size_t)P * HD;
    size_t ubase = (size_t)y * npw * HD + ch0;

    int nj = npw * 16;                         // float4 groups
    for (int j = t; j < nj; j += 256) {
        int x = j >> 4, cq = (j & 15) * 4;
        size_t off = ubase + (size_t)x * HD + cq;
        float4 s = *(const float4*)(U + off);
#pragma unroll
        for (int p = 1; p < SPLITK; ++p) {
            float4 v = *(const float4*)(U + (size_t)p * ustride + off);
            s.x += v.x; s.y += v.y; s.z += v.z; s.w += v.w;
        }
        *(float4*)&tile[x * 64 + cq] = s;
    }
    __syncthreads();

    if (t < 64) {
        int c = t;
        size_t srow = (size_t)(y + 1) * (npw + 1) * HD + ch0;
        S[srow + c] = 0.f;                     // col-0 border
        float acc = 0.f;
        for (int x = 0; x < npw; ++x) {
            acc += tile[x * 64 + c];
            S[srow + (size_t)(x + 1) * HD + c] = acc;
        }
    }
}

// ---------------------------------------------------------------------------
// K3: block (x, chalf): stage column x (y=1..nph) through LDS via DMA
// (dest = round*4096 + t*16, wave-uniform + lane*16), y-scan, write back.
// ---------------------------------------------------------------------------
__global__ __launch_bounds__(256) void prefix_y_kernel(
    float* __restrict__ S, int npw, int nph)
{
    extern __shared__ float tile[];            // nph*64 floats
    int t = threadIdx.x;
    int x = blockIdx.x;
    int ch0 = blockIdx.y * 64;
    size_t stride = (size_t)(npw + 1) * HD;
    size_t base = (size_t)x * HD + ch0;

    int nj = nph * 16;
    for (int j = t; j < nj; j += 256) {
        int y = j >> 4, cq = (j & 15) * 4;
        __builtin_amdgcn_global_load_lds(
            (const GLOBAL_AS unsigned int*)(S + base + (size_t)(y + 1) * stride + cq),
            (LDS_AS unsigned int*)&tile[y * 64 + cq], 16, 0, 0);
    }
    __syncthreads();

    if (t < 64) {
        int c = t;
        S[base + c] = 0.f;                     // row-0 border
        float acc = 0.f;
        for (int y = 0; y < nph; ++y) {
            acc += tile[y * 64 + c];
            S[base + (size_t)(y + 1) * stride + c] = acc;
        }
    }
}

// ---------------------------------------------------------------------------
// K4: 16 boxes x 128 cols; parallel LN stats; fp32 out. W2 staged via DMA
// (call i: dest byte = i*4096 + t*16 == Bs[i*8 + t>>5][(t&31)*4]).
// ---------------------------------------------------------------------------
__global__ __launch_bounds__(256) void pool_proj_kernel(
    const float* __restrict__ S, const int* __restrict__ bboxes,
    const int* __restrict__ pH, const int* __restrict__ pW,
    const float* __restrict__ b1, const float* __restrict__ gamma,
    const float* __restrict__ beta, const float* __restrict__ W2,
    const float* __restrict__ b2, float* __restrict__ out,
    int Nb, int npw, int nph, int fbW, int fbH)
{
    __shared__ float hs[16][HD + 1];
    __shared__ float Bs[32][HD];
    __shared__ float red_s[16][17], red_q[16][17];
    __shared__ int   cI11[16], cI12[16], cI21[16], cI22[16];
    __shared__ float cCnt[16];
    __shared__ float mu_s[16], rs_s[16];

    int t = threadIdx.x;
    int c = t & 127;
    int rh = t >> 7;
    int row0 = blockIdx.x * 16;

    if (t < 16) {
        int b = row0 + t; if (b >= Nb) b = Nb - 1;
        int x1 = bboxes[b * 4 + 0];
        int y1 = bboxes[b * 4 + 1];
        int x2 = bboxes[b * 4 + 2];
        int y2 = bboxes[b * 4 + 3];
        int Wi = decode_dim(pW, fbW);
        int Hi = decode_dim(pH, fbH);
        int px1 = coord_map(x1, Wi, npw);
        int px2 = coord_map(x2, Wi, npw);
        int py1 = coord_map(y1, Hi, nph);
        int py2 = coord_map(y2, Hi, nph);
        px1 = min(max(px1, 0), npw - 1);
        px2 = max(px1 + 1, min(px2, npw));
        py1 = min(max(py1, 0), nph - 1);
        py2 = max(py1 + 1, min(py2, nph));
        int st = npw + 1;
        cI11[t] = (py1 * st + px1) * HD;
        cI12[t] = (py1 * st + px2) * HD;
        cI21[t] = (py2 * st + px1) * HD;
        cI22[t] = (py2 * st + px2) * HD;
        cCnt[t] = (float)((py2 - py1) * (px2 - px1));
    }
    __syncthreads();

    float bias1 = b1[c];
    float hv[8];
#pragma unroll
    for (int r = 0; r < 8; ++r) {
        int row = rh * 8 + r;
        float s = S[cI22[row] + c] - S[cI12[row] + c]
                - S[cI21[row] + c] + S[cI11[row] + c];
        hv[r] = s / cCnt[row] + bias1;
        hs[row][c] = hv[r];
    }
    __syncthreads();

    // parallel LN stats: 16 threads per row, 8 elements each
    {
        int sr = t & 15;           // row
        int sg = t >> 4;           // group 0..15
        float ps = 0.f, pq = 0.f;
#pragma unroll
        for (int i = 0; i < 8; ++i) {
            float v = hs[sr][sg * 8 + i];
            ps += v; pq += v * v;
        }
        red_s[sr][sg] = ps; red_q[sr][sg] = pq;
    }
    __syncthreads();
    if (t < 16) {
        float s = 0.f, q = 0.f;
#pragma unroll
        for (int i = 0; i < 16; ++i) { s += red_s[t][i]; q += red_q[t][i]; }
        float m = s * (1.0f / HD);
        float v = q * (1.0f / HD) - m * m;
        mu_s[t] = m;
        rs_s[t] = rsqrtf(v + 1e-5f);
    }
    __syncthreads();

    float g = gamma[c], be = beta[c];
#pragma unroll
    for (int r = 0; r < 8; ++r) {
        int row = rh * 8 + r;
        float x = (hv[r] - mu_s[row]) * rs_s[row] * g + be;
        hs[row][c] = fmaxf(x, 0.f);
    }
    __syncthreads();

    float bias2 = b2[c];
    float acc2[8];
#pragma unroll
    for (int r = 0; r < 8; ++r) acc2[r] = bias2;
    for (int k0 = 0; k0 < HD; k0 += 32) {
#pragma unroll
        for (int i = 0; i < 4; ++i) {
            int kk = i * 8 + (t >> 5);
            int cc = (t & 31) * 4;
            __builtin_amdgcn_global_load_lds(
                (const GLOBAL_AS unsigned int*)&W2[(size_t)(k0 + kk) * HD + cc],
                (LDS_AS unsigned int*)&Bs[kk][cc], 16, 0, 0);
        }
        __syncthreads();
#pragma unroll
        for (int kk = 0; kk < 32; ++kk) {
            float bv = Bs[kk][c];
#pragma unroll
            for (int r = 0; r < 8; ++r)
                acc2[r] += hs[rh * 8 + r][k0 + kk] * bv;
        }
        __syncthreads();
    }

#pragma unroll
    for (int r = 0; r < 8; ++r) {
        int rg = row0 + rh * 8 + r;
        if (rg < Nb) out[(size_t)rg * HD + c] = acc2[r];
    }
}

extern "C" void kernel_launch(void* const* d_in, const int* in_sizes, int n_in,
                              void* d_out, int out_size, void* d_ws, size_t ws_size,
                              hipStream_t stream) {
    int iT = 0, iB = 1, iH = 2, iW = 3, iW1 = 4, ib1 = 5, ig = 6, ibe = 7,
        iW2 = 8, ib2 = 9;
    bool has_scalars = (n_in >= 10 && in_sizes[2] == 1 && in_sizes[3] == 1);
    if (!has_scalars) { iW1 = 2; ib1 = 3; ig = 4; ibe = 5; iW2 = 6; ib2 = 7; }

    const float* tokens = (const float*)d_in[iT];
    const int*   bboxes = (const int*)d_in[iB];
    const int*   pH     = has_scalars ? (const int*)d_in[iH] : nullptr;
    const int*   pW     = has_scalars ? (const int*)d_in[iW] : nullptr;
    const float* W1     = (const float*)d_in[iW1];
    const float* b1     = (const float*)d_in[ib1];
    const float* gamma  = (const float*)d_in[ig];
    const float* beta   = (const float*)d_in[ibe];
    const float* W2     = (const float*)d_in[iW2];
    const float* b2     = (const float*)d_in[ib2];
    float* out = (float*)d_out;

    int Hd = in_sizes[ib1];               // 128
    int E  = in_sizes[iW1] / Hd;          // 1024
    int Nb = in_sizes[iB] / 4;            // 4096
    int P  = in_sizes[iT] / E;            // 5476
    int npw = 1;
    while ((npw + 1) * (npw + 1) <= P) ++npw;  // 74
    int nph = P / npw;
    (void)out_size; (void)ws_size;

    // Workspace: S (2.88 MB) + 4 partial U buffers (11.2 MB) = 14.1 MB
    float* S = (float*)d_ws;
    size_t s_elems = ((size_t)(nph + 1) * (npw + 1) * HD + 255) & ~(size_t)255;
    float* U = S + s_elems;

    int mtiles = (P + 31) / 32;
    gemm_u_kernel<<<dim3(mtiles, SPLITK), dim3(256), 0, stream>>>(
        tokens, W1, U, P, E);
    prefix_x_kernel<<<dim3(nph, 2), dim3(256), (size_t)npw * 64 * 4, stream>>>(
        U, S, P, npw, nph);
    prefix_y_kernel<<<dim3(npw + 1, 2), dim3(256), (size_t)nph * 64 * 4, stream>>>(
        S, npw, nph);
    pool_proj_kernel<<<dim3((Nb + 15) / 16), dim3(256), 0, stream>>>(
        S, bboxes, pH, pW, b1, gamma, beta, W2, b2, out, Nb, npw, nph,
        14 * npw, 14 * nph);
}